// Round 1
// 633.726 us; speedup vs baseline: 14.0274x; 14.0274x over previous
//
#include <hip/hip_runtime.h>

#define NB 4096
#define NSEQ 64
#define CDIM 96
#define NH 3

typedef __attribute__((ext_vector_type(8))) short bf16x8;
typedef __attribute__((ext_vector_type(4))) float f32x4;
typedef unsigned short u16;

#define MFMA16 __builtin_amdgcn_mfma_f32_16x16x32_bf16

__device__ __forceinline__ u16 f2bf(float f) {
  unsigned u = __builtin_bit_cast(unsigned, f);
  u += 0x7FFFu + ((u >> 16) & 1u);
  return (u16)(u >> 16);
}

// ---------------- bias precompute directly in MFMA D-fragment layout:
// biasF[(t*3+h)*16 + fr*4+fc][lane] = float4 over r, value = tbl_t[rel[n][m], h]
// with m = 16*fr + 4*(lane>>4) + r (D row), n = 16*fc + (lane&15) (D col).
__global__ __launch_bounds__(256) void bias_pre_kernel(
    const float* __restrict__ tcv, const float* __restrict__ tsv,
    const float* __restrict__ tch, const float* __restrict__ tsh,
    const int* __restrict__ rel, float* __restrict__ biasF) {
  int idx = blockIdx.x * 256 + threadIdx.x;
  if (idx >= 4 * 3 * 16 * 64) return;
  int t = idx / (3 * 16 * 64);
  int r0 = idx % (3 * 16 * 64);
  int h = r0 / (16 * 64);
  int r1 = r0 % (16 * 64);
  int frag = r1 >> 6;
  int lane = r1 & 63;
  int fr = frag >> 2, fc = frag & 3;
  int g = lane >> 4, q = lane & 15;
  int n = 16 * fc + q;
  int m0 = 16 * fr + 4 * g;
  const float* tbl = (t == 0) ? tcv : (t == 1) ? tsv : (t == 2) ? tch : tsh;
  float4 v;
  v.x = tbl[rel[n * 64 + m0 + 0] * NH + h];
  v.y = tbl[rel[n * 64 + m0 + 1] * NH + h];
  v.z = tbl[rel[n * 64 + m0 + 2] * NH + h];
  v.w = tbl[rel[n * 64 + m0 + 3] * NH + h];
  ((float4*)biasF)[idx] = v;
}

// ---------------- weight fp32 -> bf16 (RNE) conversion
// layout in dst (u16 units): Ws[0..36864) We[36864..73728) Wpv[73728..92160) Wph[92160..110592)
__global__ __launch_bounds__(256) void wcvt_kernel(
    const float* __restrict__ Ws, const float* __restrict__ We,
    const float* __restrict__ Wpv, const float* __restrict__ Wph,
    u16* __restrict__ dst) {
  int i = blockIdx.x * 256 + threadIdx.x;
  if (i >= 110592) return;
  float v;
  if (i < 36864) v = Ws[i];
  else if (i < 73728) v = We[i - 36864];
  else if (i < 92160) v = Wpv[i - 73728];
  else v = Wph[i - 92160];
  dst[i] = f2bf(v);
}

// ---------------- main fused kernel: one block per window, wave w = attn type
// w0: cv (q=qsv(S), K=ks(S), V=vs(S), sc)   w1: sv (qev(E), ke, ve, 1)
// w2: ch (qeh(E), ke, ve, sc)               w3: sh (qsh(S), ks, vs, sc^2)
// All GEMMs on mfma_f32_16x16x32_bf16. Frag conventions (gfx950):
//   A: row=lane&15, k=8*(lane>>4)+j ; B: col=lane&15, k=8*(lane>>4)+j
//   D: col=lane&15, row=4*(lane>>4)+r
__global__ __launch_bounds__(256, 2) void rwa_kernel(
    const float* __restrict__ Xin, const float* __restrict__ Xst,
    const float* __restrict__ bs, const float* __restrict__ be,
    const float* __restrict__ bpv, const float* __restrict__ bph,
    const float* __restrict__ biasF, const u16* __restrict__ wbf,
    float* __restrict__ out) {
  const int b = blockIdx.x;
  const int t = threadIdx.x;
  const int wu = __builtin_amdgcn_readfirstlane(t >> 6);
  const int lane = t & 63;
  const int g = lane >> 4;
  const int q = lane & 15;

  // LDS map (u16 units):
  // KS[64][40]=0  KE=2560  VEt[32][72]=5120  VSt=7424
  // Q[w][64][40]=9728+w*2560   P[w][64][72]=19968+w*4608  (O[w][64][40] overlays P[w])
  __shared__ __align__(16) u16 lds[38400];  // 76800 B -> 2 blocks/CU

  const int KS_u = 0, KE_u = 2560, VEt_u = 5120, VSt_u = 7424;
  const int Q_u = 9728 + wu * 2560;
  const int P_u = 19968 + wu * 4608;

  const float SC = 0.17677669529663687f;  // 32^-0.5
  const bool isS = (wu == 0 || wu == 3);
  const float* X = isS ? Xst : Xin;
  const u16* Wt = isS ? (wbf + 0) : (wbf + 36864);
  const float* bt = isS ? bs : be;
  const int qf = (wu < 2) ? 2 : 3;
  const int sf = (wu < 2) ? 0 : 1;
  const int kb_u = (wu == 1 || wu == 2) ? KE_u : KS_u;
  const int vb_u = (wu == 1 || wu == 2) ? VEt_u : VSt_u;
  const int stage_u = (wu == 0) ? KS_u : (wu == 1) ? KE_u : (wu == 2) ? VEt_u : VSt_u;
  const float sc = (wu == 0 || wu == 2) ? SC : ((wu == 1) ? 1.0f : SC * SC);

  const u16* WpvB = wbf + 73728;
  const u16* WphB = wbf + 92160;

  // ---- X A-fragments (held across all heads): row n = 16*fa+q, k = 32*kc+8*g+j
  bf16x8 xa[4][3];
#pragma unroll
  for (int fa = 0; fa < 4; fa++) {
    const float* xrow = X + ((size_t)b * NSEQ + 16 * fa + q) * CDIM;
#pragma unroll
    for (int kc = 0; kc < 3; kc++) {
      float xr[8];
      *(float4*)&xr[0] = *(const float4*)(xrow + 32 * kc + 8 * g);
      *(float4*)&xr[4] = *(const float4*)(xrow + 32 * kc + 8 * g + 4);
      bf16x8 v;
#pragma unroll
      for (int j = 0; j < 8; j++) v[j] = (short)f2bf(xr[j]);
      xa[fa][kc] = v;
    }
  }

  // ---- final-projection accumulators: rows n=16*wu+4g+r, cols c=16*fc+q
  f32x4 accO[6], accS[6];
#pragma unroll
  for (int i = 0; i < 6; i++) {
    accO[i] = (f32x4){0.f, 0.f, 0.f, 0.f};
    accS[i] = (f32x4){0.f, 0.f, 0.f, 0.f};
  }

#pragma unroll 1
  for (int h = 0; h < NH; h++) {
    // ================= phase 1: projections (q + shared slice), MFMA
    f32x4 pd[4][4];
#pragma unroll
    for (int fa = 0; fa < 4; fa++)
#pragma unroll
      for (int fc = 0; fc < 4; fc++) pd[fa][fc] = (f32x4){0.f, 0.f, 0.f, 0.f};

#pragma unroll
    for (int kc = 0; kc < 3; kc++) {
      bf16x8 bw[4];
#pragma unroll
      for (int fc = 0; fc < 4; fc++) {
        int ch = ((fc < 2) ? qf : sf) * CDIM + h * 32 + (fc & 1) * 16 + q;
        bw[fc] = *(const bf16x8*)&Wt[(size_t)ch * CDIM + 32 * kc + 8 * g];
      }
#pragma unroll
      for (int fa = 0; fa < 4; fa++)
#pragma unroll
        for (int fc = 0; fc < 4; fc++)
          pd[fa][fc] = MFMA16(xa[fa][kc], bw[fc], pd[fa][fc], 0, 0, 0);
    }
    float bq[4];
#pragma unroll
    for (int fc = 0; fc < 4; fc++)
      bq[fc] = bt[((fc < 2) ? qf : sf) * CDIM + h * 32 + (fc & 1) * 16 + q];

    // stage to LDS as bf16. q and K: row-major [n][d]; V: transposed [d][m]
#pragma unroll
    for (int fa = 0; fa < 4; fa++) {
#pragma unroll
      for (int fc = 0; fc < 2; fc++)
#pragma unroll
        for (int r = 0; r < 4; r++) {
          int n = 16 * fa + 4 * g + r;
          lds[Q_u + n * 40 + 16 * fc + q] = f2bf(pd[fa][fc][r] + bq[fc]);
        }
      if (wu < 2) {
#pragma unroll
        for (int fc = 2; fc < 4; fc++)
#pragma unroll
          for (int r = 0; r < 4; r++) {
            int n = 16 * fa + 4 * g + r;
            lds[stage_u + n * 40 + 16 * (fc - 2) + q] = f2bf(pd[fa][fc][r] + bq[fc]);
          }
      } else {
#pragma unroll
        for (int fc = 2; fc < 4; fc++) {
          int d = 16 * (fc - 2) + q;
          ushort4 pk;
          pk.x = f2bf(pd[fa][fc][0] + bq[fc]);
          pk.y = f2bf(pd[fa][fc][1] + bq[fc]);
          pk.z = f2bf(pd[fa][fc][2] + bq[fc]);
          pk.w = f2bf(pd[fa][fc][3] + bq[fc]);
          *(ushort4*)&lds[stage_u + d * 72 + 16 * fa + 4 * g] = pk;
        }
      }
    }
    __syncthreads();

    // ================= phase 2a: Lt = K·Q^T  (Lt[m][n] = logit(n,m))
    f32x4 lt[4][4];
#pragma unroll
    for (int fr = 0; fr < 4; fr++)
#pragma unroll
      for (int fc = 0; fc < 4; fc++) lt[fr][fc] = (f32x4){0.f, 0.f, 0.f, 0.f};
    bf16x8 ka[4], qb[4];
#pragma unroll
    for (int fr = 0; fr < 4; fr++)
      ka[fr] = *(const bf16x8*)&lds[kb_u + (16 * fr + q) * 40 + 8 * g];
#pragma unroll
    for (int fc = 0; fc < 4; fc++)
      qb[fc] = *(const bf16x8*)&lds[Q_u + (16 * fc + q) * 40 + 8 * g];
#pragma unroll
    for (int fr = 0; fr < 4; fr++)
#pragma unroll
      for (int fc = 0; fc < 4; fc++)
        lt[fr][fc] = MFMA16(ka[fr], qb[fc], lt[fr][fc], 0, 0, 0);

    // scale + bias (pre-gathered in frag layout)
    const float4* bfp = ((const float4*)biasF) + (size_t)((wu * 3 + h) * 16) * 64 + lane;
#pragma unroll
    for (int fr = 0; fr < 4; fr++)
#pragma unroll
      for (int fc = 0; fc < 4; fc++) {
        float4 bv = bfp[(fr * 4 + fc) * 64];
        lt[fr][fc][0] = sc * lt[fr][fc][0] + bv.x;
        lt[fr][fc][1] = sc * lt[fr][fc][1] + bv.y;
        lt[fr][fc][2] = sc * lt[fr][fc][2] + bv.z;
        lt[fr][fc][3] = sc * lt[fr][fc][3] + bv.w;
      }

    // softmax over m per column n (16 in-lane values + xor-16/32 across g-groups)
#pragma unroll
    for (int fc = 0; fc < 4; fc++) {
      float mx = lt[0][fc][0];
#pragma unroll
      for (int fr = 0; fr < 4; fr++)
#pragma unroll
        for (int r = 0; r < 4; r++) mx = fmaxf(mx, lt[fr][fc][r]);
      mx = fmaxf(mx, __shfl_xor(mx, 16));
      mx = fmaxf(mx, __shfl_xor(mx, 32));
      float s = 0.f;
#pragma unroll
      for (int fr = 0; fr < 4; fr++)
#pragma unroll
        for (int r = 0; r < 4; r++) {
          float p = __expf(lt[fr][fc][r] - mx);
          lt[fr][fc][r] = p;
          s += p;
        }
      s += __shfl_xor(s, 16);
      s += __shfl_xor(s, 32);
      float inv = 1.0f / s;
      // write normalized P row-major [n][m], 4 consecutive m packed per write
#pragma unroll
      for (int fr = 0; fr < 4; fr++) {
        ushort4 pk;
        pk.x = f2bf(lt[fr][fc][0] * inv);
        pk.y = f2bf(lt[fr][fc][1] * inv);
        pk.z = f2bf(lt[fr][fc][2] * inv);
        pk.w = f2bf(lt[fr][fc][3] * inv);
        *(ushort4*)&lds[P_u + (16 * fc + q) * 72 + 16 * fr + 4 * g] = pk;
      }
    }

    // ================= phase 2b: O^T = V^T · P^T  (Ot[d][n])
    f32x4 ot[2][4];
#pragma unroll
    for (int fa = 0; fa < 2; fa++)
#pragma unroll
      for (int fc = 0; fc < 4; fc++) ot[fa][fc] = (f32x4){0.f, 0.f, 0.f, 0.f};
#pragma unroll
    for (int kc = 0; kc < 2; kc++) {
      bf16x8 va[2], pb[4];
#pragma unroll
      for (int fa = 0; fa < 2; fa++)
        va[fa] = *(const bf16x8*)&lds[vb_u + (16 * fa + q) * 72 + 32 * kc + 8 * g];
#pragma unroll
      for (int fc = 0; fc < 4; fc++)
        pb[fc] = *(const bf16x8*)&lds[P_u + (16 * fc + q) * 72 + 32 * kc + 8 * g];
#pragma unroll
      for (int fa = 0; fa < 2; fa++)
#pragma unroll
        for (int fc = 0; fc < 4; fc++)
          ot[fa][fc] = MFMA16(va[fa], pb[fc], ot[fa][fc], 0, 0, 0);
    }
    // stage O[n][d] (bf16) into own (now dead) P region, 4 consecutive d per write
#pragma unroll
    for (int fa = 0; fa < 2; fa++)
#pragma unroll
      for (int fc = 0; fc < 4; fc++) {
        ushort4 pk;
        pk.x = f2bf(ot[fa][fc][0]);
        pk.y = f2bf(ot[fa][fc][1]);
        pk.z = f2bf(ot[fa][fc][2]);
        pk.w = f2bf(ot[fa][fc][3]);
        *(ushort4*)&lds[P_u + (16 * fc + q) * 40 + 16 * fa + 4 * g] = pk;
      }
    __syncthreads();

    // ================= phase 3: accumulate out/state projections (per-head K-chunk)
    bf16x8 ao[4];
#pragma unroll
    for (int tt = 0; tt < 4; tt++)
      ao[tt] = *(const bf16x8*)&lds[19968 + tt * 4608 + (16 * wu + q) * 40 + 8 * g];
#pragma unroll
    for (int fc = 0; fc < 6; fc++) {
      int c = 16 * fc + q;
      bf16x8 b0 = *(const bf16x8*)&WpvB[(size_t)c * 192 + h * 32 + 8 * g];
      bf16x8 b1 = *(const bf16x8*)&WpvB[(size_t)c * 192 + 96 + h * 32 + 8 * g];
      accO[fc] = MFMA16(ao[0], b0, accO[fc], 0, 0, 0);
      accO[fc] = MFMA16(ao[1], b1, accO[fc], 0, 0, 0);
      bf16x8 b2 = *(const bf16x8*)&WphB[(size_t)c * 192 + h * 32 + 8 * g];
      bf16x8 b3 = *(const bf16x8*)&WphB[(size_t)c * 192 + 96 + h * 32 + 8 * g];
      accS[fc] = MFMA16(ao[2], b2, accS[fc], 0, 0, 0);
      accS[fc] = MFMA16(ao[3], b3, accS[fc], 0, 0, 0);
    }
    // no barrier needed: next head's stage writes touch only q/K/V regions,
    // and next P writes are fenced by the next __syncthreads() above.
  }

  // ================= epilogue: wave wu owns rows 16*wu..16*wu+15
  float* orow = out + (size_t)b * NSEQ * CDIM;
  float* srow = orow + (size_t)NB * NSEQ * CDIM;
#pragma unroll
  for (int fc = 0; fc < 6; fc++) {
    int c = 16 * fc + q;
    float bo = bpv[c], bh2 = bph[c];
#pragma unroll
    for (int r = 0; r < 4; r++) {
      int n = 16 * wu + 4 * g + r;
      orow[(size_t)n * CDIM + c] = accO[fc][r] + bo;
      srow[(size_t)n * CDIM + c] = accS[fc][r] + bh2;
    }
  }
}

extern "C" void kernel_launch(void* const* d_in, const int* in_sizes, int n_in,
                              void* d_out, int out_size, void* d_ws, size_t ws_size,
                              hipStream_t stream) {
  const float* input_x = (const float*)d_in[0];
  const float* state_x = (const float*)d_in[1];
  const float* Ws   = (const float*)d_in[2];
  const float* bs   = (const float*)d_in[3];
  const float* We   = (const float*)d_in[4];
  const float* be   = (const float*)d_in[5];
  const float* tcv  = (const float*)d_in[6];
  const float* tsv  = (const float*)d_in[7];
  const float* tch  = (const float*)d_in[8];
  const float* tsh  = (const float*)d_in[9];
  const float* Wpv  = (const float*)d_in[10];
  const float* bpv  = (const float*)d_in[11];
  const float* Wph  = (const float*)d_in[12];
  const float* bph  = (const float*)d_in[13];
  const int*   rel  = (const int*)d_in[14];

  float* biasF = (float*)d_ws;                          // 196608 B
  u16* wbf = (u16*)((char*)d_ws + 196608);              // 221184 B bf16 weights

  bias_pre_kernel<<<48, 256, 0, stream>>>(tcv, tsv, tch, tsh, rel, biasF);
  wcvt_kernel<<<432, 256, 0, stream>>>(Ws, We, Wpv, Wph, wbf);
  rwa_kernel<<<NB, 256, 0, stream>>>(input_x, state_x, bs, be, bpv, bph,
                                     biasF, wbf, (float*)d_out);
}